// Round 5
// baseline (65.099 us; speedup 1.0000x reference)
//
#include <hip/hip_runtime.h>
#include <hip/hip_bf16.h>
#include <stdint.h>

typedef float  f32x4  __attribute__((ext_vector_type(4)));
typedef __bf16 bf16x4 __attribute__((ext_vector_type(4)));
typedef __bf16 bf16x8 __attribute__((ext_vector_type(8)));
typedef unsigned int u32x2 __attribute__((ext_vector_type(2)));
typedef unsigned int u32x4 __attribute__((ext_vector_type(4)));

#define AS1 __attribute__((address_space(1)))
#define AS3 __attribute__((address_space(3)))

__device__ __forceinline__ void async_load16(const void* g, void* lds) {
    __builtin_amdgcn_global_load_lds((const AS1 unsigned int*)g,
                                     (AS3 unsigned int*)lds, 16, 0, 0);
}

// ---------------------------------------------------------------------------
// K1: qw[hs][k] = scale * sum_d q[h,s,d] * Wk[k, h*64+d]   (bf16 out, [hs][768])
// ---------------------------------------------------------------------------
__global__ __launch_bounds__(256) void qw_kernel(const float* __restrict__ q_emb,
                                                 const float* __restrict__ wk,
                                                 __bf16* __restrict__ qwT) {
    __shared__ float qlds[256];
    __shared__ float part[4096];  // [k 64][s 4][dseg 16]
    const int t = threadIdx.x;
    const int kc = blockIdx.x;   // 0..11
    const int h  = blockIdx.y;   // 0..15
    const int k0 = kc * 64;
    qlds[t] = q_emb[h * 256 + t] * 0.125f;   // scale = D^-0.5 = 1/8
    __syncthreads();
    const int dseg = t & 15;
    const int krow = t >> 4;   // 0..15
#pragma unroll
    for (int i = 0; i < 4; ++i) {
        const int k = i * 16 + krow;
        f32x4 wv = *(const f32x4*)&wk[(size_t)(k0 + k) * 1024 + h * 64 + dseg * 4];
#pragma unroll
        for (int s = 0; s < 4; ++s) {
            float p = qlds[s * 64 + dseg * 4 + 0] * wv[0]
                    + qlds[s * 64 + dseg * 4 + 1] * wv[1]
                    + qlds[s * 64 + dseg * 4 + 2] * wv[2]
                    + qlds[s * 64 + dseg * 4 + 3] * wv[3];
            part[k * 64 + s * 16 + dseg] = p;
        }
    }
    __syncthreads();
    const int k = t >> 2, s = t & 3;
    const float* pp = &part[k * 64 + s * 16];
    float sum = 0.f;
#pragma unroll
    for (int j = 0; j < 16; ++j) sum += pp[j];
    qwT[(h * 4 + s) * 768 + k0 + k] = (__bf16)sum;
}

// ---------------------------------------------------------------------------
// K2: logits[b][hs][n] = sum_k x[b,n,k]*qw[hs,k], eos-masked, + per-chunk
// softmax partials. BM=64 -> grid 512 (2 blocks/CU), 512 thr (8 waves 4Mx2N).
// ---------------------------------------------------------------------------
__global__ __launch_bounds__(512, 4) void logits_kernel(const float* __restrict__ x,
                                                        const __bf16* __restrict__ qwT,
                                                        const int* __restrict__ eos_idx,
                                                        float* __restrict__ Lg,
                                                        float* __restrict__ partials) {
    __shared__ char smem[32768];
    char* Bl = smem;           // 2 x 8 KB  [col 64][k 64] bf16, XOR ((col&7)<<4)
    char* Al = smem + 16384;   // 2 x 8 KB  [row 64][k 64] bf16, XOR ((row&7)<<4)
    const int t = threadIdx.x, l = t & 63, w = t >> 6;
    const int m0 = blockIdx.x * 64;
    const int bb = m0 >> 10, n0 = m0 & 1023;
    const int chunk = (m0 >> 6) & 15;
    const int wm = (w >> 1) * 16;  // m(=n of attn) frag base, 0..48
    const int wh = (w & 1) * 32;   // hs base, 0/32

    f32x4 acc[2];
    acc[0] = (f32x4)0.f; acc[1] = (f32x4)0.f;

    const int Bcol = t >> 3, Bseg = t & 7;
    const __bf16* qsrc = qwT + Bcol * 768 + (Bseg ^ (Bcol & 7)) * 8;
    const int Arow = t >> 3;   // 0..63
    const float* xrow = &x[(size_t)(m0 + Arow) * 768 + (t & 7) * 8];
    const int Adst = (Arow * 128 + (t & 7) * 16) ^ ((Arow & 7) << 4);

    f32x4 av0, av1;
    // ---- prologue (kt = 0)
    async_load16(qsrc, Bl + t * 16);
    av0 = *(const f32x4*)(xrow);
    av1 = *(const f32x4*)(xrow + 4);
    {
        bf16x8 v;
        v[0] = (__bf16)av0[0]; v[1] = (__bf16)av0[1];
        v[2] = (__bf16)av0[2]; v[3] = (__bf16)av0[3];
        v[4] = (__bf16)av1[0]; v[5] = (__bf16)av1[1];
        v[6] = (__bf16)av1[2]; v[7] = (__bf16)av1[3];
        *(bf16x8*)(Al + Adst) = v;
    }
    asm volatile("s_waitcnt vmcnt(0)" ::: "memory");
    __syncthreads();

    int buf = 0;
    for (int step = 0; step < 12; ++step) {
        const int nbuf = buf ^ 1;
        const bool more = (step + 1) < 12;
        if (more) {
            const int kt = (step + 1) * 64;
            async_load16(qsrc + kt, Bl + nbuf * 8192 + t * 16);
            av0 = *(const f32x4*)(xrow + kt);
            av1 = *(const f32x4*)(xrow + kt + 4);
        }
#pragma unroll
        for (int kh = 0; kh < 2; ++kh) {
            const int u = kh * 4 + (l >> 4);
            const int arow = wm + (l & 15);
            bf16x8 af = *(const bf16x8*)(Al + buf * 8192 +
                                         ((arow * 128 + u * 16) ^ ((arow & 7) << 4)));
            bf16x8 bfr[2];
#pragma unroll
            for (int j = 0; j < 2; ++j) {
                const int col = wh + j * 16 + (l & 15);
                bfr[j] = *(const bf16x8*)(Bl + buf * 8192 +
                                          ((col * 128 + u * 16) ^ ((col & 7) << 4)));
            }
#pragma unroll
            for (int j = 0; j < 2; ++j)
                acc[j] = __builtin_amdgcn_mfma_f32_16x16x32_bf16(af, bfr[j], acc[j], 0, 0, 0);
        }
        if (more) {
            bf16x8 v;
            v[0] = (__bf16)av0[0]; v[1] = (__bf16)av0[1];
            v[2] = (__bf16)av0[2]; v[3] = (__bf16)av0[3];
            v[4] = (__bf16)av1[0]; v[5] = (__bf16)av1[1];
            v[6] = (__bf16)av1[2]; v[7] = (__bf16)av1[3];
            *(bf16x8*)(Al + nbuf * 8192 + Adst) = v;
        }
        asm volatile("s_waitcnt vmcnt(0)" ::: "memory");
        __syncthreads();
        buf = nbuf;
    }

    // ---- epilogue: frags -> smem [hs 64][n 64] f32 -> mask, stats, store
#pragma unroll
    for (int j = 0; j < 2; ++j) {
        const int hs = wh + j * 16 + (l & 15);
        const int nb = wm + (l >> 4) * 4;
        *(f32x4*)(smem + ((hs * 256 + nb * 4) ^ ((hs & 7) << 4))) = acc[j];
    }
    __syncthreads();
    const int eosb = eos_idx[bb];
    const int hs = t >> 3, seg = t & 7;
    const int fH = (hs & 7) << 4;
    f32x4 v0 = *(const f32x4*)(smem + ((hs * 256 + seg * 32) ^ fH));
    f32x4 v1 = *(const f32x4*)(smem + ((hs * 256 + seg * 32 + 16) ^ fH));
    const int nbase = n0 + seg * 8;
    float mx = -INFINITY;
#pragma unroll
    for (int j = 0; j < 4; ++j) {
        if (nbase + j > eosb) v0[j] = -INFINITY;
        if (nbase + 4 + j > eosb) v1[j] = -INFINITY;
        mx = fmaxf(mx, fmaxf(v0[j], v1[j]));
    }
    *(f32x4*)&Lg[(size_t)bb * 65536 + hs * 1024 + nbase] = v0;
    *(f32x4*)&Lg[(size_t)bb * 65536 + hs * 1024 + nbase + 4] = v1;
#pragma unroll
    for (int off = 1; off < 8; off <<= 1) mx = fmaxf(mx, __shfl_xor(mx, off));
    float sl = 0.f;
    if (mx > -INFINITY) {
#pragma unroll
        for (int j = 0; j < 4; ++j) sl += __expf(v0[j] - mx) + __expf(v1[j] - mx);
    }
#pragma unroll
    for (int off = 1; off < 8; off <<= 1) sl += __shfl_xor(sl, off);
    if (seg == 0) {
        float2 st = {mx, sl};
        *(float2*)&partials[(size_t)(((bb * 16 + chunk) * 64) + hs) * 2] = st;
    }
}

// ---------------------------------------------------------------------------
// K3: y[nh][b][hs][k] partial = sum_{n in half nh} softmax(Lg) * x[b,n,k]
// grid 768 = 32 b x 12 kc x 2 nh (3 blocks/CU exactly), 256 thr, 8 steps.
// T14 order: issue loads -> MFMA -> exp/pack/ds_write -> barrier.
// ---------------------------------------------------------------------------
__global__ __launch_bounds__(256, 3) void pv_kernel(const float* __restrict__ x,
                                                    const float* __restrict__ Lg,
                                                    const float* __restrict__ partials,
                                                    float* __restrict__ y) {
    __shared__ char smem[32768];
    char* Pl = smem;           // 2 x 8 KB  [hs 64][n 64] bf16, XOR ((row&7)<<4)
    char* Xl = smem + 16384;   // 2 x 8 KB  [k 64][n 64] bf16, XOR fK
    const int t = threadIdx.x, l = t & 63, w = t >> 6;
    const int vid = (blockIdx.x & 7) * 96 + (blockIdx.x >> 3);  // bijective XCD swizzle
    const int b = vid / 24, rem = vid % 24;
    const int kc = rem % 12, nh = rem / 12;
    const int k0 = kc * 64, nbase = nh * 512;
    const int wrA = (w >> 1) * 32, wcB = (w & 1) * 32;
    const float* Lgb = Lg + (size_t)b * 65536;
    const float* xb = x + (size_t)b * 786432 + k0 + l;   // this thread's k-column
    const int fK = ((l & 7) << 4) | (((l >> 3) & 1) << 3);

    // ---- combine softmax partials (16 chunks) for this thread's two rows
    const int r0 = t >> 3, r1 = 32 + (t >> 3);
    float m0r, i0r, m1r, i1r;
    {
        const float* pb = partials + (size_t)b * 2048;  // [chunk 16][hs 64] float2
        float m = -INFINITY, m2 = -INFINITY;
#pragma unroll
        for (int c = 0; c < 16; ++c) {
            m  = fmaxf(m,  pb[(c * 64 + r0) * 2]);
            m2 = fmaxf(m2, pb[(c * 64 + r1) * 2]);
        }
        float s = 0.f, s2 = 0.f;
#pragma unroll
        for (int c = 0; c < 16; ++c) {
            float2 p0 = *(const float2*)&pb[(c * 64 + r0) * 2];
            float2 p1 = *(const float2*)&pb[(c * 64 + r1) * 2];
            s  += p0.y * __expf(p0.x - m);
            s2 += p1.y * __expf(p1.x - m2);
        }
        m0r = m; i0r = 1.0f / s;
        m1r = m2; i1r = 1.0f / s2;
    }
    const int n0s0 = (((t & 7) ^ (r0 & 7)) * 8);
    const int n0s1 = (((t & 7) ^ (r1 & 7)) * 8);

    f32x4 acc[2][2];
#pragma unroll
    for (int i = 0; i < 2; ++i)
#pragma unroll
        for (int j = 0; j < 2; ++j) acc[i][j] = (f32x4)0.f;

    float xv[16];
    f32x4 plo0, phi0, plo1, phi1;

    // ---- prologue: stage tile 0
    plo0 = *(const f32x4*)&Lgb[(size_t)r0 * 1024 + nbase + n0s0];
    phi0 = *(const f32x4*)&Lgb[(size_t)r0 * 1024 + nbase + n0s0 + 4];
    plo1 = *(const f32x4*)&Lgb[(size_t)r1 * 1024 + nbase + n0s1];
    phi1 = *(const f32x4*)&Lgb[(size_t)r1 * 1024 + nbase + n0s1 + 4];
#pragma unroll
    for (int i = 0; i < 4; ++i)
#pragma unroll
        for (int j = 0; j < 4; ++j)
            xv[i * 4 + j] = xb[(size_t)(nbase + i * 16 + w * 4 + j) * 768];
    {
        bf16x8 pk;
#pragma unroll
        for (int j = 0; j < 4; ++j) pk[j]     = (__bf16)(__expf(plo0[j] - m0r) * i0r);
#pragma unroll
        for (int j = 0; j < 4; ++j) pk[4 + j] = (__bf16)(__expf(phi0[j] - m0r) * i0r);
        *(bf16x8*)(Pl + t * 16) = pk;
#pragma unroll
        for (int j = 0; j < 4; ++j) pk[j]     = (__bf16)(__expf(plo1[j] - m1r) * i1r);
#pragma unroll
        for (int j = 0; j < 4; ++j) pk[4 + j] = (__bf16)(__expf(phi1[j] - m1r) * i1r);
        *(bf16x8*)(Pl + 4096 + t * 16) = pk;
#pragma unroll
        for (int i = 0; i < 4; ++i) {
            bf16x4 vv = {(__bf16)xv[i * 4 + 0], (__bf16)xv[i * 4 + 1],
                         (__bf16)xv[i * 4 + 2], (__bf16)xv[i * 4 + 3]};
            *(bf16x4*)(Xl + ((l * 128 + (i * 16 + w * 4) * 2) ^ fK)) = vv;
        }
    }
    __syncthreads();

    int buf = 0;
    for (int step = 0; step < 8; ++step) {
        const int nbuf = buf ^ 1;
        const bool more = (step + 1) < 8;
        if (more) {
            const int nt = nbase + (step + 1) * 64;
            plo0 = *(const f32x4*)&Lgb[(size_t)r0 * 1024 + nt + n0s0];
            phi0 = *(const f32x4*)&Lgb[(size_t)r0 * 1024 + nt + n0s0 + 4];
            plo1 = *(const f32x4*)&Lgb[(size_t)r1 * 1024 + nt + n0s1];
            phi1 = *(const f32x4*)&Lgb[(size_t)r1 * 1024 + nt + n0s1 + 4];
#pragma unroll
            for (int i = 0; i < 4; ++i)
#pragma unroll
                for (int j = 0; j < 4; ++j)
                    xv[i * 4 + j] = xb[(size_t)(nt + i * 16 + w * 4 + j) * 768];
        }
#pragma unroll
        for (int kh = 0; kh < 2; ++kh) {
            const int u = kh * 4 + (l >> 4);
            bf16x8 af[2], bfr[2];
#pragma unroll
            for (int i = 0; i < 2; ++i) {
                const int row = wrA + i * 16 + (l & 15);
                af[i] = *(const bf16x8*)(Pl + buf * 8192 +
                                         ((row * 128 + u * 16) ^ ((row & 7) << 4)));
            }
#pragma unroll
            for (int j = 0; j < 2; ++j) {
                const int kcol = wcB + j * 16 + (l & 15);
                const int fKc = ((kcol & 7) << 4) | (((kcol >> 3) & 1) << 3);
                const int addrA = kcol * 128 + kh * 64 + (l >> 4) * 16;
                u32x2 lo = *(const u32x2*)(Xl + buf * 8192 + (addrA ^ fKc));
                u32x2 hi = *(const u32x2*)(Xl + buf * 8192 + ((addrA + 8) ^ fKc));
                u32x4 uu = {lo[0], lo[1], hi[0], hi[1]};
                bfr[j] = __builtin_bit_cast(bf16x8, uu);
            }
#pragma unroll
            for (int i = 0; i < 2; ++i)
#pragma unroll
                for (int j = 0; j < 2; ++j)
                    acc[i][j] = __builtin_amdgcn_mfma_f32_16x16x32_bf16(
                        af[i], bfr[j], acc[i][j], 0, 0, 0);
        }
        if (more) {
            bf16x8 pk;
#pragma unroll
            for (int j = 0; j < 4; ++j) pk[j]     = (__bf16)(__expf(plo0[j] - m0r) * i0r);
#pragma unroll
            for (int j = 0; j < 4; ++j) pk[4 + j] = (__bf16)(__expf(phi0[j] - m0r) * i0r);
            *(bf16x8*)(Pl + nbuf * 8192 + t * 16) = pk;
#pragma unroll
            for (int j = 0; j < 4; ++j) pk[j]     = (__bf16)(__expf(plo1[j] - m1r) * i1r);
#pragma unroll
            for (int j = 0; j < 4; ++j) pk[4 + j] = (__bf16)(__expf(phi1[j] - m1r) * i1r);
            *(bf16x8*)(Pl + nbuf * 8192 + 4096 + t * 16) = pk;
#pragma unroll
            for (int i = 0; i < 4; ++i) {
                bf16x4 vv = {(__bf16)xv[i * 4 + 0], (__bf16)xv[i * 4 + 1],
                             (__bf16)xv[i * 4 + 2], (__bf16)xv[i * 4 + 3]};
                *(bf16x4*)(Xl + nbuf * 8192 + ((l * 128 + (i * 16 + w * 4) * 2) ^ fK)) = vv;
            }
        }
        __syncthreads();
        buf = nbuf;
    }

    // ---- epilogue: frag -> LDS [hs 64][k 64] f32 -> coalesced global
#pragma unroll
    for (int i = 0; i < 2; ++i)
#pragma unroll
        for (int j = 0; j < 2; ++j) {
            const int kcol = wcB + j * 16 + (l & 15);
#pragma unroll
            for (int r = 0; r < 4; ++r) {
                const int hs2 = wrA + i * 16 + (l >> 4) * 4 + r;
                *(float*)(smem + ((hs2 * 256 + kcol * 4) ^ ((hs2 & 7) << 4))) = acc[i][j][r];
            }
        }
    __syncthreads();
    float* yh = y + (size_t)nh * 1572864;
    const int hs2 = t >> 2;
#pragma unroll
    for (int i = 0; i < 4; ++i) {
        const int seg = (t & 3) + i * 4;
        f32x4 v = *(const f32x4*)(smem + ((hs2 * 256 + seg * 16) ^ ((hs2 & 7) << 4)));
        *(f32x4*)&yh[(size_t)(b * 64 + hs2) * 768 + k0 + seg * 4] = v;
    }
}

// ---------------------------------------------------------------------------
// K4: out[b][hs][d] = sum_k (y0+y1)[b,hs,k]*Wk[k,h*64+d] + bk[h*64+d]
// 256 blocks = (h 16) x (b-pair 16), 256 thr = 4 k-partitions x 64 d.
// ---------------------------------------------------------------------------
__global__ __launch_bounds__(256) void out_kernel(const float* __restrict__ y,
                                                  const float* __restrict__ wk,
                                                  const float* __restrict__ bk,
                                                  float* __restrict__ out) {
    __shared__ float ylds[8 * 768];  // 24 KB
    __shared__ float red[2048];      // 8 KB
    const int t = threadIdx.x;
    const int vid = (blockIdx.x & 7) * 32 + (blockIdx.x >> 3);  // same-h grouped per XCD
    const int h = vid >> 4, bp = vid & 15;
#pragma unroll
    for (int r = 0; r < 8; ++r) {
        const int gb = bp * 2 + (r >> 2);
        const int hs = h * 4 + (r & 3);
#pragma unroll
        for (int i = 0; i < 3; ++i) {
            const size_t idx = (size_t)(gb * 64 + hs) * 768 + i * 256 + t;
            ylds[r * 768 + i * 256 + t] = y[idx] + y[idx + 1572864];
        }
    }
    __syncthreads();
    const int kp = t >> 6, d = t & 63;
    float acc[8] = {0.f, 0.f, 0.f, 0.f, 0.f, 0.f, 0.f, 0.f};
    for (int i = 0; i < 48; ++i) {
        const int k = kp * 192 + i * 4;
        const float wv0 = wk[(size_t)(k + 0) * 1024 + h * 64 + d];
        const float wv1 = wk[(size_t)(k + 1) * 1024 + h * 64 + d];
        const float wv2 = wk[(size_t)(k + 2) * 1024 + h * 64 + d];
        const float wv3 = wk[(size_t)(k + 3) * 1024 + h * 64 + d];
#pragma unroll
        for (int r = 0; r < 8; ++r) {
            f32x4 yv = *(const f32x4*)&ylds[r * 768 + k];
            acc[r] += yv[0] * wv0 + yv[1] * wv1 + yv[2] * wv2 + yv[3] * wv3;
        }
    }
#pragma unroll
    for (int r = 0; r < 8; ++r) red[(r * 64 + d) * 4 + kp] = acc[r];
    __syncthreads();
#pragma unroll
    for (int i = 0; i < 2; ++i) {
        const int o = i * 256 + t;
        const int r = o >> 6, dd = o & 63;
        f32x4 pv = *(const f32x4*)&red[o * 4];
        const float s = pv[0] + pv[1] + pv[2] + pv[3] + bk[h * 64 + dd];
        const int gb = bp * 2 + (r >> 2);
        out[(size_t)(gb * 64 + h * 4 + (r & 3)) * 64 + dd] = s;
    }
}

// ---------------------------------------------------------------------------
extern "C" void kernel_launch(void* const* d_in, const int* in_sizes, int n_in,
                              void* d_out, int out_size, void* d_ws, size_t ws_size,
                              hipStream_t stream) {
    const float* x     = (const float*)d_in[0];   // (32,1024,768)
    const int*   eos   = (const int*)d_in[1];     // (32,)
    const float* q_emb = (const float*)d_in[2];   // (16,4,64)
    const float* Wk    = (const float*)d_in[3];   // (768,1024)
    const float* bk    = (const float*)d_in[4];   // (1024,)
    float* out = (float*)d_out;

    char* ws = (char*)d_ws;
    __bf16* qwT      = (__bf16*)ws;                     // 96 KB  [hs 64][k 768]
    float*  Lg       = (float*)(ws + 131072);           // 8 MB   [b][hs][n]
    float*  partials = (float*)(ws + 8519680);          // 256 KB [b][chunk 16][hs][2]
    float*  y        = (float*)(ws + 8781824);          // 12 MB  [nh 2][b][hs][k]

    qw_kernel<<<dim3(12, 16), 256, 0, stream>>>(q_emb, Wk, qwT);
    logits_kernel<<<dim3(512), 512, 0, stream>>>(x, qwT, eos, Lg, partials);
    pv_kernel<<<dim3(768), 256, 0, stream>>>(x, Lg, partials, y);
    out_kernel<<<dim3(256), 256, 0, stream>>>(y, Wk, bk, out);
}

// Round 6
// 63.886 us; speedup vs baseline: 1.0190x; 1.0190x over previous
//
#include <hip/hip_runtime.h>
#include <hip/hip_bf16.h>
#include <stdint.h>

typedef float  f32x4  __attribute__((ext_vector_type(4)));
typedef __bf16 bf16x4 __attribute__((ext_vector_type(4)));
typedef __bf16 bf16x8 __attribute__((ext_vector_type(8)));
typedef unsigned int u32x2 __attribute__((ext_vector_type(2)));
typedef unsigned int u32x4 __attribute__((ext_vector_type(4)));

#define AS1 __attribute__((address_space(1)))
#define AS3 __attribute__((address_space(3)))

__device__ __forceinline__ void async_load16(const void* g, void* lds) {
    __builtin_amdgcn_global_load_lds((const AS1 unsigned int*)g,
                                     (AS3 unsigned int*)lds, 16, 0, 0);
}

// ---------------------------------------------------------------------------
// K1: qw[hs][k] = scale * sum_d q[h,s,d] * Wk[k, h*64+d]   (bf16 out, [hs][768])
// ---------------------------------------------------------------------------
__global__ __launch_bounds__(256) void qw_kernel(const float* __restrict__ q_emb,
                                                 const float* __restrict__ wk,
                                                 __bf16* __restrict__ qwT) {
    __shared__ float qlds[256];
    __shared__ float part[4096];  // [k 64][s 4][dseg 16]
    const int t = threadIdx.x;
    const int kc = blockIdx.x;   // 0..11
    const int h  = blockIdx.y;   // 0..15
    const int k0 = kc * 64;
    qlds[t] = q_emb[h * 256 + t] * 0.125f;   // scale = D^-0.5 = 1/8
    __syncthreads();
    const int dseg = t & 15;
    const int krow = t >> 4;   // 0..15
#pragma unroll
    for (int i = 0; i < 4; ++i) {
        const int k = i * 16 + krow;
        f32x4 wv = *(const f32x4*)&wk[(size_t)(k0 + k) * 1024 + h * 64 + dseg * 4];
#pragma unroll
        for (int s = 0; s < 4; ++s) {
            float p = qlds[s * 64 + dseg * 4 + 0] * wv[0]
                    + qlds[s * 64 + dseg * 4 + 1] * wv[1]
                    + qlds[s * 64 + dseg * 4 + 2] * wv[2]
                    + qlds[s * 64 + dseg * 4 + 3] * wv[3];
            part[k * 64 + s * 16 + dseg] = p;
        }
    }
    __syncthreads();
    const int k = t >> 2, s = t & 3;
    const float* pp = &part[k * 64 + s * 16];
    float sum = 0.f;
#pragma unroll
    for (int j = 0; j < 16; ++j) sum += pp[j];
    qwT[(h * 4 + s) * 768 + k0 + k] = (__bf16)sum;
}

// ---------------------------------------------------------------------------
// K2: logits[b][hs][n] = sum_k x[b,n,k]*qw[hs,k], eos-masked, + per-chunk
// softmax partials. BM=64 -> grid 512, 512 thr (8 waves, 4Mx2N).
// Pipelined: raw s_barrier + counted vmcnt; x reg-prefetch depth 2.
// ---------------------------------------------------------------------------
__device__ __forceinline__ void lg_compute(const char* Al, const char* Bl, int buf,
                                           int wm, int wh, int l, f32x4* acc) {
#pragma unroll
    for (int kh = 0; kh < 2; ++kh) {
        const int u = kh * 4 + (l >> 4);
        const int arow = wm + (l & 15);
        bf16x8 af = *(const bf16x8*)(Al + buf * 8192 +
                                     ((arow * 128 + u * 16) ^ ((arow & 7) << 4)));
#pragma unroll
        for (int j = 0; j < 2; ++j) {
            const int col = wh + j * 16 + (l & 15);
            bf16x8 bfr = *(const bf16x8*)(Bl + buf * 8192 +
                                          ((col * 128 + u * 16) ^ ((col & 7) << 4)));
            acc[j] = __builtin_amdgcn_mfma_f32_16x16x32_bf16(af, bfr, acc[j], 0, 0, 0);
        }
    }
}

__global__ __launch_bounds__(512, 4) void logits_kernel(const float* __restrict__ x,
                                                        const __bf16* __restrict__ qwT,
                                                        const int* __restrict__ eos_idx,
                                                        float* __restrict__ Lg,
                                                        float* __restrict__ partials) {
    __shared__ char smem[32768];
    char* Bl = smem;           // 2 x 8 KB  [col 64][k 64] bf16, XOR ((col&7)<<4)
    char* Al = smem + 16384;   // 2 x 8 KB  [row 64][k 64] bf16, XOR ((row&7)<<4)
    const int t = threadIdx.x, l = t & 63, w = t >> 6;
    const int m0 = blockIdx.x * 64;
    const int bb = m0 >> 10, n0 = m0 & 1023;
    const int chunk = (m0 >> 6) & 15;
    const int wm = (w >> 1) * 16;  // m frag base, 0..48
    const int wh = (w & 1) * 32;   // hs base, 0/32

    f32x4 acc[2];
    acc[0] = (f32x4)0.f; acc[1] = (f32x4)0.f;

    const int Bcol = t >> 3, Bseg = t & 7;
    const __bf16* qsrc = qwT + Bcol * 768 + (Bseg ^ (Bcol & 7)) * 8;
    const int Arow = t >> 3;   // 0..63
    const float* xrow = &x[(size_t)(m0 + Arow) * 768 + (t & 7) * 8];
    const int Adst = (Arow * 128 + (t & 7) * 16) ^ ((Arow & 7) << 4);

    f32x4 xa0, xa1, xb0, xb1, xc0, xc1;

#define LG_ISSUE_B(T, BUF) async_load16(qsrc + (T) * 64, Bl + (BUF) * 8192 + t * 16)
#define LG_ISSUE_X(R0, R1, T) { R0 = *(const f32x4*)(xrow + (T) * 64); \
                                R1 = *(const f32x4*)(xrow + (T) * 64 + 4); }
#define LG_WRITE_X(R0, R1, BUF) { bf16x8 v_; \
    v_[0]=(__bf16)R0[0]; v_[1]=(__bf16)R0[1]; v_[2]=(__bf16)R0[2]; v_[3]=(__bf16)R0[3]; \
    v_[4]=(__bf16)R1[0]; v_[5]=(__bf16)R1[1]; v_[6]=(__bf16)R1[2]; v_[7]=(__bf16)R1[3]; \
    *(bf16x8*)(Al + (BUF) * 8192 + Adst) = v_; }

    // ---- prologue: B0 async; x0,x1,x2 in regs; write x0
    LG_ISSUE_B(0, 0);
    __builtin_amdgcn_sched_barrier(0);
    LG_ISSUE_X(xa0, xa1, 0);
    LG_ISSUE_X(xb0, xb1, 1);
    LG_ISSUE_X(xc0, xc1, 2);
    LG_WRITE_X(xa0, xa1, 0);               // compiler waits x0 -> drains B0 too
    asm volatile("s_waitcnt lgkmcnt(0)" ::: "memory");
    asm volatile("s_waitcnt vmcnt(4)" ::: "memory");   // leave x1,x2 in flight
    __builtin_amdgcn_s_barrier();

    int buf = 0;
    // steady steps t=0..8: issue B(t+1); issue x(t+3); compute(t); write x(t+1)
#define LG_STEP(T, W0, W1, I0, I1) { \
    const int nbuf = buf ^ 1; \
    LG_ISSUE_B((T) + 1, nbuf); \
    __builtin_amdgcn_sched_barrier(0); \
    LG_ISSUE_X(I0, I1, (T) + 3); \
    lg_compute(Al, Bl, buf, wm, wh, l, acc); \
    LG_WRITE_X(W0, W1, nbuf); \
    asm volatile("s_waitcnt lgkmcnt(0)" ::: "memory"); \
    asm volatile("s_waitcnt vmcnt(2)" ::: "memory"); \
    __builtin_amdgcn_s_barrier(); \
    buf = nbuf; }

    for (int it = 0; it < 3; ++it) {
        const int tb = it * 3;
        LG_STEP(tb + 0, xb0, xb1, xa0, xa1);
        LG_STEP(tb + 1, xc0, xc1, xb0, xb1);
        LG_STEP(tb + 2, xa0, xa1, xc0, xc1);
    }
    // tail t=9,10,11
    {
        const int nbuf = buf ^ 1;
        LG_ISSUE_B(10, nbuf);
        __builtin_amdgcn_sched_barrier(0);
        lg_compute(Al, Bl, buf, wm, wh, l, acc);
        LG_WRITE_X(xb0, xb1, nbuf);        // x10
        asm volatile("s_waitcnt lgkmcnt(0)" ::: "memory");
        asm volatile("s_waitcnt vmcnt(0)" ::: "memory");
        __builtin_amdgcn_s_barrier();
        buf = nbuf;
    }
    {
        const int nbuf = buf ^ 1;
        LG_ISSUE_B(11, nbuf);
        __builtin_amdgcn_sched_barrier(0);
        lg_compute(Al, Bl, buf, wm, wh, l, acc);
        LG_WRITE_X(xc0, xc1, nbuf);        // x11
        asm volatile("s_waitcnt lgkmcnt(0)" ::: "memory");
        asm volatile("s_waitcnt vmcnt(0)" ::: "memory");
        __builtin_amdgcn_s_barrier();
        buf = nbuf;
    }
    lg_compute(Al, Bl, buf, wm, wh, l, acc);
    __syncthreads();

    // ---- epilogue: frags -> smem [hs 64][n 64] f32 -> mask, stats, store
#pragma unroll
    for (int j = 0; j < 2; ++j) {
        const int hs = wh + j * 16 + (l & 15);
        const int nb = wm + (l >> 4) * 4;
        *(f32x4*)(smem + ((hs * 256 + nb * 4) ^ ((hs & 7) << 4))) = acc[j];
    }
    __syncthreads();
    const int eosb = eos_idx[bb];
    const int hs = t >> 3, seg = t & 7;
    const int fH = (hs & 7) << 4;
    f32x4 v0 = *(const f32x4*)(smem + ((hs * 256 + seg * 32) ^ fH));
    f32x4 v1 = *(const f32x4*)(smem + ((hs * 256 + seg * 32 + 16) ^ fH));
    const int nbase = n0 + seg * 8;
    float mx = -INFINITY;
#pragma unroll
    for (int j = 0; j < 4; ++j) {
        if (nbase + j > eosb) v0[j] = -INFINITY;
        if (nbase + 4 + j > eosb) v1[j] = -INFINITY;
        mx = fmaxf(mx, fmaxf(v0[j], v1[j]));
    }
    *(f32x4*)&Lg[(size_t)bb * 65536 + hs * 1024 + nbase] = v0;
    *(f32x4*)&Lg[(size_t)bb * 65536 + hs * 1024 + nbase + 4] = v1;
#pragma unroll
    for (int off = 1; off < 8; off <<= 1) mx = fmaxf(mx, __shfl_xor(mx, off));
    float sl = 0.f;
    if (mx > -INFINITY) {
#pragma unroll
        for (int j = 0; j < 4; ++j) sl += __expf(v0[j] - mx) + __expf(v1[j] - mx);
    }
#pragma unroll
    for (int off = 1; off < 8; off <<= 1) sl += __shfl_xor(sl, off);
    if (seg == 0) {
        float2 st = {mx, sl};
        *(float2*)&partials[(size_t)(((bb * 16 + chunk) * 64) + hs) * 2] = st;
    }
}

// ---------------------------------------------------------------------------
// K3: y[nh][b][hs][k] partial = sum_{n in half nh} softmax(Lg) * x[b,n,k]
// grid 768 = 32 b x 12 kc x 2 nh, 256 thr, 8 steps. Depth-2 reg prefetch,
// raw barriers with lgkmcnt-only (all loads span barriers).
// ---------------------------------------------------------------------------
__device__ __forceinline__ void pv_compute(const char* Pl, const char* Xl, int buf,
                                           int wrA, int wcB, int l, f32x4 (*acc)[2]) {
#pragma unroll
    for (int kh = 0; kh < 2; ++kh) {
        const int u = kh * 4 + (l >> 4);
        bf16x8 af[2], bfr[2];
#pragma unroll
        for (int i = 0; i < 2; ++i) {
            const int row = wrA + i * 16 + (l & 15);
            af[i] = *(const bf16x8*)(Pl + buf * 8192 +
                                     ((row * 128 + u * 16) ^ ((row & 7) << 4)));
        }
#pragma unroll
        for (int j = 0; j < 2; ++j) {
            const int kcol = wcB + j * 16 + (l & 15);
            const int fKc = ((kcol & 7) << 4) | (((kcol >> 3) & 1) << 3);
            const int addrA = kcol * 128 + kh * 64 + (l >> 4) * 16;
            u32x2 lo = *(const u32x2*)(Xl + buf * 8192 + (addrA ^ fKc));
            u32x2 hi = *(const u32x2*)(Xl + buf * 8192 + ((addrA + 8) ^ fKc));
            u32x4 uu = {lo[0], lo[1], hi[0], hi[1]};
            bfr[j] = __builtin_bit_cast(bf16x8, uu);
        }
#pragma unroll
        for (int i = 0; i < 2; ++i)
#pragma unroll
            for (int j = 0; j < 2; ++j)
                acc[i][j] = __builtin_amdgcn_mfma_f32_16x16x32_bf16(
                    af[i], bfr[j], acc[i][j], 0, 0, 0);
    }
}

__global__ __launch_bounds__(256, 3) void pv_kernel(const float* __restrict__ x,
                                                    const float* __restrict__ Lg,
                                                    const float* __restrict__ partials,
                                                    float* __restrict__ y) {
    __shared__ char smem[32768];
    char* Pl = smem;           // 2 x 8 KB  [hs 64][n 64] bf16, XOR ((row&7)<<4)
    char* Xl = smem + 16384;   // 2 x 8 KB  [k 64][n 64] bf16, XOR fK
    const int t = threadIdx.x, l = t & 63, w = t >> 6;
    const int vid = (blockIdx.x & 7) * 96 + (blockIdx.x >> 3);  // bijective XCD swizzle
    const int b = vid / 24, rem = vid % 24;
    const int kc = rem % 12, nh = rem / 12;
    const int k0 = kc * 64, nbase = nh * 512;
    const int wrA = (w >> 1) * 32, wcB = (w & 1) * 32;
    const float* Lgb = Lg + (size_t)b * 65536;
    const float* xb = x + (size_t)b * 786432 + k0 + l;   // this thread's k-column
    const int fK = ((l & 7) << 4) | (((l >> 3) & 1) << 3);

    // ---- combine softmax partials (16 chunks) for this thread's two rows
    const int r0 = t >> 3, r1 = 32 + (t >> 3);
    float m0r, i0r, m1r, i1r;
    {
        const float* pb = partials + (size_t)b * 2048;  // [chunk 16][hs 64] float2
        float m = -INFINITY, m2 = -INFINITY;
#pragma unroll
        for (int c = 0; c < 16; ++c) {
            m  = fmaxf(m,  pb[(c * 64 + r0) * 2]);
            m2 = fmaxf(m2, pb[(c * 64 + r1) * 2]);
        }
        float s = 0.f, s2 = 0.f;
#pragma unroll
        for (int c = 0; c < 16; ++c) {
            float2 p0 = *(const float2*)&pb[(c * 64 + r0) * 2];
            float2 p1 = *(const float2*)&pb[(c * 64 + r1) * 2];
            s  += p0.y * __expf(p0.x - m);
            s2 += p1.y * __expf(p1.x - m2);
        }
        m0r = m; i0r = 1.0f / s;
        m1r = m2; i1r = 1.0f / s2;
    }
    const int n0s0 = (((t & 7) ^ (r0 & 7)) * 8);
    const int n0s1 = (((t & 7) ^ (r1 & 7)) * 8);

    f32x4 acc[2][2];
#pragma unroll
    for (int i = 0; i < 2; ++i)
#pragma unroll
        for (int j = 0; j < 2; ++j) acc[i][j] = (f32x4)0.f;

    // two prefetch regsets (depth 2)
    f32x4 pAl0, pAh0, pAl1, pAh1, pBl0, pBh0, pBl1, pBh1;
    float xvA[16], xvB[16];

#define PV_ISSUE(PL0, PH0, PL1, PH1, XV, T) { \
    const int nt_ = nbase + (T) * 64; \
    PL0 = *(const f32x4*)&Lgb[(size_t)r0 * 1024 + nt_ + n0s0]; \
    PH0 = *(const f32x4*)&Lgb[(size_t)r0 * 1024 + nt_ + n0s0 + 4]; \
    PL1 = *(const f32x4*)&Lgb[(size_t)r1 * 1024 + nt_ + n0s1]; \
    PH1 = *(const f32x4*)&Lgb[(size_t)r1 * 1024 + nt_ + n0s1 + 4]; \
    _Pragma("unroll") \
    for (int i_ = 0; i_ < 4; ++i_) { \
        _Pragma("unroll") \
        for (int j_ = 0; j_ < 4; ++j_) \
            XV[i_ * 4 + j_] = xb[(size_t)(nt_ + i_ * 16 + w * 4 + j_) * 768]; } }

#define PV_PACK(PL0, PH0, PL1, PH1, XV, BUF) { \
    bf16x8 pk_; \
    _Pragma("unroll") \
    for (int j_ = 0; j_ < 4; ++j_) pk_[j_]     = (__bf16)(__expf(PL0[j_] - m0r) * i0r); \
    _Pragma("unroll") \
    for (int j_ = 0; j_ < 4; ++j_) pk_[4 + j_] = (__bf16)(__expf(PH0[j_] - m0r) * i0r); \
    *(bf16x8*)(Pl + (BUF) * 8192 + t * 16) = pk_; \
    _Pragma("unroll") \
    for (int j_ = 0; j_ < 4; ++j_) pk_[j_]     = (__bf16)(__expf(PL1[j_] - m1r) * i1r); \
    _Pragma("unroll") \
    for (int j_ = 0; j_ < 4; ++j_) pk_[4 + j_] = (__bf16)(__expf(PH1[j_] - m1r) * i1r); \
    *(bf16x8*)(Pl + (BUF) * 8192 + 4096 + t * 16) = pk_; \
    _Pragma("unroll") \
    for (int i_ = 0; i_ < 4; ++i_) { \
        bf16x4 vv_ = {(__bf16)XV[i_ * 4 + 0], (__bf16)XV[i_ * 4 + 1], \
                      (__bf16)XV[i_ * 4 + 2], (__bf16)XV[i_ * 4 + 3]}; \
        *(bf16x4*)(Xl + (BUF) * 8192 + ((l * 128 + (i_ * 16 + w * 4) * 2) ^ fK)) = vv_; } }

    // ---- prologue: issue tiles 0,1; pack tile 0
    PV_ISSUE(pAl0, pAh0, pAl1, pAh1, xvA, 0);
    PV_ISSUE(pBl0, pBh0, pBl1, pBh1, xvB, 1);
    PV_PACK(pAl0, pAh0, pAl1, pAh1, xvA, 0);
    asm volatile("s_waitcnt lgkmcnt(0)" ::: "memory");
    __builtin_amdgcn_s_barrier();

    int buf = 0;
    for (int it = 0; it < 4; ++it) {
        const int te = it * 2;          // even step
        if (te + 2 < 8) PV_ISSUE(pAl0, pAh0, pAl1, pAh1, xvA, te + 2);
        pv_compute(Pl, Xl, buf, wrA, wcB, l, acc);
        if (te + 1 < 8) {
            PV_PACK(pBl0, pBh0, pBl1, pBh1, xvB, buf ^ 1);
            asm volatile("s_waitcnt lgkmcnt(0)" ::: "memory");
            __builtin_amdgcn_s_barrier();
        }
        buf ^= 1;
        const int to = te + 1;          // odd step
        if (to + 2 < 8) PV_ISSUE(pBl0, pBh0, pBl1, pBh1, xvB, to + 2);
        pv_compute(Pl, Xl, buf, wrA, wcB, l, acc);
        if (to + 1 < 8) {
            PV_PACK(pAl0, pAh0, pAl1, pAh1, xvA, buf ^ 1);
            asm volatile("s_waitcnt lgkmcnt(0)" ::: "memory");
            __builtin_amdgcn_s_barrier();
        }
        buf ^= 1;
    }
    __syncthreads();

    // ---- epilogue: frag -> LDS [hs 64][k 64] f32 -> coalesced global
#pragma unroll
    for (int i = 0; i < 2; ++i)
#pragma unroll
        for (int j = 0; j < 2; ++j) {
            const int kcol = wcB + j * 16 + (l & 15);
#pragma unroll
            for (int r = 0; r < 4; ++r) {
                const int hs2 = wrA + i * 16 + (l >> 4) * 4 + r;
                *(float*)(smem + ((hs2 * 256 + kcol * 4) ^ ((hs2 & 7) << 4))) = acc[i][j][r];
            }
        }
    __syncthreads();
    float* yh = y + (size_t)nh * 1572864;
    const int hs2 = t >> 2;
#pragma unroll
    for (int i = 0; i < 4; ++i) {
        const int seg = (t & 3) + i * 4;
        f32x4 v = *(const f32x4*)(smem + ((hs2 * 256 + seg * 16) ^ ((hs2 & 7) << 4)));
        *(f32x4*)&yh[(size_t)(b * 64 + hs2) * 768 + k0 + seg * 4] = v;
    }
}

// ---------------------------------------------------------------------------
// K4: out[b][hs][d] = sum_k (y0+y1)[b,hs,k]*Wk[k,h*64+d] + bk[h*64+d]
// ---------------------------------------------------------------------------
__global__ __launch_bounds__(256) void out_kernel(const float* __restrict__ y,
                                                  const float* __restrict__ wk,
                                                  const float* __restrict__ bk,
                                                  float* __restrict__ out) {
    __shared__ float ylds[8 * 768];  // 24 KB
    __shared__ float red[2048];      // 8 KB
    const int t = threadIdx.x;
    const int vid = (blockIdx.x & 7) * 32 + (blockIdx.x >> 3);  // same-h grouped per XCD
    const int h = vid >> 4, bp = vid & 15;
#pragma unroll
    for (int r = 0; r < 8; ++r) {
        const int gb = bp * 2 + (r >> 2);
        const int hs = h * 4 + (r & 3);
#pragma unroll
        for (int i = 0; i < 3; ++i) {
            const size_t idx = (size_t)(gb * 64 + hs) * 768 + i * 256 + t;
            ylds[r * 768 + i * 256 + t] = y[idx] + y[idx + 1572864];
        }
    }
    __syncthreads();
    const int kp = t >> 6, d = t & 63;
    float acc[8] = {0.f, 0.f, 0.f, 0.f, 0.f, 0.f, 0.f, 0.f};
    for (int i = 0; i < 48; ++i) {
        const int k = kp * 192 + i * 4;
        const float wv0 = wk[(size_t)(k + 0) * 1024 + h * 64 + d];
        const float wv1 = wk[(size_t)(k + 1) * 1024 + h * 64 + d];
        const float wv2 = wk[(size_t)(k + 2) * 1024 + h * 64 + d];
        const float wv3 = wk[(size_t)(k + 3) * 1024 + h * 64 + d];
#pragma unroll
        for (int r = 0; r < 8; ++r) {
            f32x4 yv = *(const f32x4*)&ylds[r * 768 + k];
            acc[r] += yv[0] * wv0 + yv[1] * wv1 + yv[2] * wv2 + yv[3] * wv3;
        }
    }
#pragma unroll
    for (int r = 0; r < 8; ++r) red[(r * 64 + d) * 4 + kp] = acc[r];
    __syncthreads();
#pragma unroll
    for (int i = 0; i < 2; ++i) {
        const int o = i * 256 + t;
        const int r = o >> 6, dd = o & 63;
        f32x4 pv = *(const f32x4*)&red[o * 4];
        const float s = pv[0] + pv[1] + pv[2] + pv[3] + bk[h * 64 + dd];
        const int gb = bp * 2 + (r >> 2);
        out[(size_t)(gb * 64 + h * 4 + (r & 3)) * 64 + dd] = s;
    }
}

// ---------------------------------------------------------------------------
extern "C" void kernel_launch(void* const* d_in, const int* in_sizes, int n_in,
                              void* d_out, int out_size, void* d_ws, size_t ws_size,
                              hipStream_t stream) {
    const float* x     = (const float*)d_in[0];   // (32,1024,768)
    const int*   eos   = (const int*)d_in[1];     // (32,)
    const float* q_emb = (const float*)d_in[2];   // (16,4,64)
    const float* Wk    = (const float*)d_in[3];   // (768,1024)
    const float* bk    = (const float*)d_in[4];   // (1024,)
    float* out = (float*)d_out;

    char* ws = (char*)d_ws;
    __bf16* qwT      = (__bf16*)ws;                     // 96 KB  [hs 64][k 768]
    float*  Lg       = (float*)(ws + 131072);           // 8 MB   [b][hs][n]
    float*  partials = (float*)(ws + 8519680);          // 256 KB [b][chunk 16][hs][2]
    float*  y        = (float*)(ws + 8781824);          // 12 MB  [nh 2][b][hs][k]

    qw_kernel<<<dim3(12, 16), 256, 0, stream>>>(q_emb, Wk, qwT);
    logits_kernel<<<dim3(512), 512, 0, stream>>>(x, qwT, eos, Lg, partials);
    pv_kernel<<<dim3(768), 256, 0, stream>>>(x, Lg, partials, y);
    out_kernel<<<dim3(256), 256, 0, stream>>>(y, Wk, bk, out);
}